// Round 1
// baseline (10481.720 us; speedup 1.0000x reference)
//
#include <hip/hip_runtime.h>
#include <hip/hip_bf16.h>

// RNN LM: B=4, T=1024, E=512, H=1024, K=512, Vd=512, V=32000
// Outputs: logits[4096,32000] fp32, hidden[4096,1024] fp32, outs[4096,1024] fp32
//
// Structure:
//  - split-bf16 (hi/lo) GEMM for xp (fp32-grade), plain bf16 MFMA GEMM everywhere else
//  - persistent 16-WG recurrence kernel: Wh hi/lo fragments in VGPRs, h exchanged
//    through LLC via agent-scope atomics (packed bf16 pairs), spin barrier per step
//  - attention: S=qk^T (fp32) -> causal softmax -> P@v^T, with v produced transposed

typedef __bf16 bf16x8 __attribute__((ext_vector_type(8)));
typedef float f32x4 __attribute__((ext_vector_type(4)));
typedef unsigned long long u64;
typedef unsigned long long u64x2 __attribute__((ext_vector_type(2)));
typedef unsigned int u32;
typedef unsigned short u16;

__device__ __forceinline__ void gl2lds16(const void* g, void* l) {
  __builtin_amdgcn_global_load_lds(
      (const __attribute__((address_space(1))) unsigned int*)g,
      (__attribute__((address_space(3))) unsigned int*)l, 16, 0, 0);
}

__device__ __forceinline__ f32x4 mfma16(bf16x8 a, bf16x8 b, f32x4 c) {
  return __builtin_amdgcn_mfma_f32_16x16x32_bf16(a, b, c, 0, 0, 0);
}

// ---------------------------------------------------------------------------
// Generic NT GEMM: C[m,n] = alpha*(sum_k A[m,k]*B[n,k] + bias_col[n] + bias_row[m])
//                  (+ C_prev if accumulate). A:[M,K] bf16, B:[N,K] bf16, ld==K.
// M%128==0, N%128==0, K%32==0 (all shapes in this problem satisfy this).
// ---------------------------------------------------------------------------
__global__ __launch_bounds__(256, 2) void gemm_nt(
    const u16* __restrict__ A, const u16* __restrict__ B,
    float* __restrict__ Cf, u16* __restrict__ Cb,
    const float* __restrict__ bias_col, const float* __restrict__ bias_row,
    float alpha, int M, int N, int K,
    long batA, long batB, long batCf, long batCb, int accumulate)
{
  __shared__ u16 As[128 * 32];
  __shared__ u16 Bs[128 * 32];
  const int tid = threadIdx.x;
  const int lane = tid & 63;
  const int w = tid >> 6;
  const int bz = blockIdx.z;
  const u16* Ab = A + batA * bz;
  const u16* Bb = B + batB * bz;
  const long m0 = (long)blockIdx.y * 128;
  const long n0 = (long)blockIdx.x * 128;
  const int wm = w & 1, wn = w >> 1;
  const int frow = lane & 15, fquad = lane >> 4;

  f32x4 acc[4][4] = {};

  const int c0 = w * 64 + lane;
  const int c1 = c0 + 256;
  const int r0 = c0 >> 2, k0off = (c0 & 3) * 8;
  const int r1 = c1 >> 2, k1off = (c1 & 3) * 8;

  for (int kt = 0; kt < K; kt += 32) {
    gl2lds16(Ab + (m0 + r0) * K + kt + k0off, &As[(w * 64) * 8]);
    gl2lds16(Ab + (m0 + r1) * K + kt + k1off, &As[(256 + w * 64) * 8]);
    gl2lds16(Bb + (n0 + r0) * K + kt + k0off, &Bs[(w * 64) * 8]);
    gl2lds16(Bb + (n0 + r1) * K + kt + k1off, &Bs[(256 + w * 64) * 8]);
    __syncthreads();
    bf16x8 af[4], bfr[4];
#pragma unroll
    for (int i = 0; i < 4; ++i) {
      af[i]  = *(const bf16x8*)&As[(wm * 64 + i * 16 + frow) * 32 + fquad * 8];
      bfr[i] = *(const bf16x8*)&Bs[(wn * 64 + i * 16 + frow) * 32 + fquad * 8];
    }
#pragma unroll
    for (int i = 0; i < 4; ++i)
#pragma unroll
      for (int j = 0; j < 4; ++j)
        acc[i][j] = mfma16(af[i], bfr[j], acc[i][j]);
    __syncthreads();
  }

#pragma unroll
  for (int i = 0; i < 4; ++i) {
    const long rowb = m0 + wm * 64 + i * 16 + fquad * 4;
#pragma unroll
    for (int j = 0; j < 4; ++j) {
      const long col = n0 + wn * 64 + j * 16 + frow;
      const float bc = bias_col ? bias_col[col] : 0.0f;
#pragma unroll
      for (int r = 0; r < 4; ++r) {
        const long row = rowb + r;
        float v = acc[i][j][r] + bc;
        if (bias_row) v += bias_row[row];
        v *= alpha;
        const long idx = row * (long)N + col;
        if (accumulate) v += Cf[batCf * bz + idx];
        if (Cf) Cf[batCf * bz + idx] = v;
        if (Cb) Cb[batCb * bz + idx] =
            __builtin_bit_cast(unsigned short, (__bf16)v);
      }
    }
  }
}

// ---------------------------------------------------------------------------
// Persistent Elman recurrence. 16 WGs x 256 threads; WG g owns h rows
// [g*64, g*64+64) for all 4 chains. Wh hi/lo MFMA fragments live in VGPRs.
// h exchanged via hpk (uint = two adjacent bf16 h values), double-buffered,
// agent-scope atomics + counter barrier per step.
// ---------------------------------------------------------------------------
__global__ __launch_bounds__(256, 1) void rnn_scan(
    const u16* __restrict__ Whhi, const u16* __restrict__ Whlo,
    const float* __restrict__ xp, const float* __restrict__ bh,
    u32* __restrict__ hpk, int* __restrict__ ctr,
    float* __restrict__ hidden_f, u16* __restrict__ hidden_b)
{
  const int tid = threadIdx.x, lane = tid & 63, w = tid >> 6;
  const int g = blockIdx.x;
  const int frow = lane & 15, fquad = lane >> 4;
  const int rbase = g * 64 + w * 16;
  const int myrow = rbase + frow;
  const int bsel = lane & 3;

  // preload Wh fragments (B-operand: n = lane&15 -> h-row, k = fquad*8+j)
  bf16x8 wfh[32], wfl[32];
#pragma unroll
  for (int kt = 0; kt < 32; ++kt) {
    const long off = (long)myrow * 1024 + kt * 32 + fquad * 8;
    wfh[kt] = *(const bf16x8*)&Whhi[off];
    wfl[kt] = *(const bf16x8*)&Whlo[off];
  }
  const float bias = bh[myrow];

  for (int t = 0; t < 1024; ++t) {
    // prefetch xp for this step (independent of barrier)
    float vxp[4];
    if (lane < 16) {
#pragma unroll
      for (int b = 0; b < 4; ++b)
        vxp[b] = xp[((long)(b * 1024 + t)) * 1024 + rbase + lane];
    }

    f32x4 accs = {0.f, 0.f, 0.f, 0.f};
    if (t > 0) {
      if (tid == 0) {
        const int target = 16 * t;
        while (__hip_atomic_load(ctr, __ATOMIC_ACQUIRE,
                                 __HIP_MEMORY_SCOPE_AGENT) < target)
          __builtin_amdgcn_s_sleep(2);
      }
      __syncthreads();

      u32* hb = hpk + ((t + 1) & 1) * 2048 + bsel * 512;  // read buffer
      bf16x8 hf[32];
#pragma unroll
      for (int kt = 0; kt < 32; ++kt) {
        u64* p = (u64*)(hb + kt * 16 + fquad * 4);
        const u64 lo64 =
            __hip_atomic_load(p, __ATOMIC_RELAXED, __HIP_MEMORY_SCOPE_AGENT);
        const u64 hi64 =
            __hip_atomic_load(p + 1, __ATOMIC_RELAXED, __HIP_MEMORY_SCOPE_AGENT);
        u64x2 tmp = {lo64, hi64};
        hf[kt] = __builtin_bit_cast(bf16x8, tmp);
      }
      f32x4 a0 = {}, a1 = {}, a2 = {}, a3 = {};
#pragma unroll
      for (int kt = 0; kt < 32; kt += 2) {
        a0 = mfma16(hf[kt], wfh[kt], a0);
        a1 = mfma16(hf[kt], wfl[kt], a1);
        a2 = mfma16(hf[kt + 1], wfh[kt + 1], a2);
        a3 = mfma16(hf[kt + 1], wfl[kt + 1], a3);
      }
      accs = (a0 + a1) + (a2 + a3);
    }

    // epilogue: lanes 0..15 hold C rows m=0..3 (=b) for col r=rbase+lane
    if (lane < 16) {
      const int r = rbase + lane;
      u32 packed[4];
#pragma unroll
      for (int b = 0; b < 4; ++b) {
        float v = accs[b] + vxp[b] + bias;
        v = fmaxf(v, 0.0f);
        const long oidx = ((long)(b * 1024 + t)) * 1024 + r;
        hidden_f[oidx] = v;
        const __bf16 hb16 = (__bf16)v;
        const unsigned short self = __builtin_bit_cast(unsigned short, hb16);
        hidden_b[oidx] = self;
        const unsigned short part = (unsigned short)__shfl_xor((int)self, 1);
        packed[b] = (u32)self | ((u32)part << 16);
      }
      if ((lane & 1) == 0) {
        u32* hw = hpk + (t & 1) * 2048;  // write buffer
#pragma unroll
        for (int b = 0; b < 4; ++b)
          __hip_atomic_store(hw + b * 512 + (r >> 1), packed[b],
                             __ATOMIC_RELAXED, __HIP_MEMORY_SCOPE_AGENT);
      }
    }
    __syncthreads();  // drains vmcnt: all stores globally visible
    if (tid == 0)
      __hip_atomic_fetch_add(ctr, 1, __ATOMIC_RELEASE,
                             __HIP_MEMORY_SCOPE_AGENT);
  }
}

// ---------------------------------------------------------------------------
// Causal softmax over S rows; writes bf16 P with zeros above the diagonal.
// ---------------------------------------------------------------------------
__global__ void softmax_causal_k(const float* __restrict__ S, u16* __restrict__ P)
{
  const int row = blockIdx.x;  // b*1024 + t
  const int t = row & 1023;
  const float* s = S + (long)row * 1024;
  u16* p = P + (long)row * 1024;
  const int n = t + 1;
  const int tid = threadIdx.x;

  float v[4];
  float m = -3.0e38f;
#pragma unroll
  for (int i = 0; i < 4; ++i) {
    const int idx = tid + i * 256;
    v[i] = (idx < n) ? s[idx] : -3.0e38f;
    m = fmaxf(m, v[i]);
  }
#pragma unroll
  for (int d = 1; d < 64; d <<= 1) m = fmaxf(m, __shfl_xor(m, d));
  __shared__ float redm[4];
  const int w = tid >> 6;
  if ((tid & 63) == 0) redm[w] = m;
  __syncthreads();
  m = fmaxf(fmaxf(redm[0], redm[1]), fmaxf(redm[2], redm[3]));

  float sum = 0.f;
#pragma unroll
  for (int i = 0; i < 4; ++i) {
    const int idx = tid + i * 256;
    v[i] = (idx < n) ? __expf(v[i] - m) : 0.f;
    sum += v[i];
  }
#pragma unroll
  for (int d = 1; d < 64; d <<= 1) sum += __shfl_xor(sum, d);
  __shared__ float reds[4];
  if ((tid & 63) == 0) reds[w] = sum;
  __syncthreads();
  sum = reds[0] + reds[1] + reds[2] + reds[3];
  const float inv = 1.0f / sum;
#pragma unroll
  for (int i = 0; i < 4; ++i) {
    const int idx = tid + i * 256;
    p[idx] = __builtin_bit_cast(unsigned short, (__bf16)(v[i] * inv));
  }
}

// ---------------------------------------------------------------------------
// Embedding gather + hi/lo split; weight split/cast helpers.
// ---------------------------------------------------------------------------
__global__ void embed_split_k(const int* __restrict__ tokens,
                              const float* __restrict__ emb,
                              u16* __restrict__ xhi, u16* __restrict__ xlo)
{
  const int m = blockIdx.x;
  const int tok = tokens[m];
  const float4 v = ((const float4*)(emb + (long)tok * 512))[threadIdx.x];
  const float xs[4] = {v.x, v.y, v.z, v.w};
  unsigned short hh[4], ll[4];
#pragma unroll
  for (int c = 0; c < 4; ++c) {
    const __bf16 hb = (__bf16)xs[c];
    hh[c] = __builtin_bit_cast(unsigned short, hb);
    ll[c] = __builtin_bit_cast(unsigned short, (__bf16)(xs[c] - (float)hb));
  }
  const long base = (long)m * 512 + threadIdx.x * 4;
  *(uint2*)&xhi[base] =
      make_uint2((u32)hh[0] | ((u32)hh[1] << 16), (u32)hh[2] | ((u32)hh[3] << 16));
  *(uint2*)&xlo[base] =
      make_uint2((u32)ll[0] | ((u32)ll[1] << 16), (u32)ll[2] | ((u32)ll[3] << 16));
}

__global__ void split_f32_k(const float* __restrict__ in, u16* __restrict__ hi,
                            u16* __restrict__ lo, long n4)
{
  const long i = (long)blockIdx.x * 256 + threadIdx.x;
  if (i >= n4) return;
  const float4 v = ((const float4*)in)[i];
  const float xs[4] = {v.x, v.y, v.z, v.w};
  unsigned short hh[4], ll[4];
#pragma unroll
  for (int c = 0; c < 4; ++c) {
    const __bf16 hb = (__bf16)xs[c];
    hh[c] = __builtin_bit_cast(unsigned short, hb);
    ll[c] = __builtin_bit_cast(unsigned short, (__bf16)(xs[c] - (float)hb));
  }
  ((uint2*)hi)[i] =
      make_uint2((u32)hh[0] | ((u32)hh[1] << 16), (u32)hh[2] | ((u32)hh[3] << 16));
  ((uint2*)lo)[i] =
      make_uint2((u32)ll[0] | ((u32)ll[1] << 16), (u32)ll[2] | ((u32)ll[3] << 16));
}

__global__ void cast_f32_k(const float* __restrict__ in, u16* __restrict__ outb,
                           long n4)
{
  const long i = (long)blockIdx.x * 256 + threadIdx.x;
  if (i >= n4) return;
  const float4 v = ((const float4*)in)[i];
  const float xs[4] = {v.x, v.y, v.z, v.w};
  unsigned short hh[4];
#pragma unroll
  for (int c = 0; c < 4; ++c)
    hh[c] = __builtin_bit_cast(unsigned short, (__bf16)xs[c]);
  ((uint2*)outb)[i] =
      make_uint2((u32)hh[0] | ((u32)hh[1] << 16), (u32)hh[2] | ((u32)hh[3] << 16));
}

// ---------------------------------------------------------------------------
extern "C" void kernel_launch(void* const* d_in, const int* in_sizes, int n_in,
                              void* d_out, int out_size, void* d_ws, size_t ws_size,
                              hipStream_t stream)
{
  const int*   tokens = (const int*)d_in[0];
  const float* emb    = (const float*)d_in[1];
  const float* Wi     = (const float*)d_in[2];
  const float* bi     = (const float*)d_in[3];
  const float* Wh     = (const float*)d_in[4];
  const float* bh     = (const float*)d_in[5];
  const float* Wro    = (const float*)d_in[6];
  const float* bro    = (const float*)d_in[7];
  const float* Wq     = (const float*)d_in[8];
  const float* bq     = (const float*)d_in[9];
  const float* Wk     = (const float*)d_in[10];
  const float* bk     = (const float*)d_in[11];
  const float* Wv     = (const float*)d_in[12];
  const float* bv     = (const float*)d_in[13];
  const float* Wao    = (const float*)d_in[14];
  const float* bao    = (const float*)d_in[15];
  const float* Wlm    = (const float*)d_in[16];
  const float* blm    = (const float*)d_in[17];
  float* out = (float*)d_out;
  char* ws = (char*)d_ws;

  // workspace layout (bytes)
  size_t off = 0;
  auto nxt = [&](size_t bytes) {
    size_t r = off;
    off += (bytes + 255) & ~(size_t)255;
    return r;
  };
  u16* xhi   = (u16*)(ws + nxt(4096ul * 512 * 2));
  u16* xlo   = (u16*)(ws + nxt(4096ul * 512 * 2));
  u16* Wihi  = (u16*)(ws + nxt(1024ul * 512 * 2));
  u16* Wilo  = (u16*)(ws + nxt(1024ul * 512 * 2));
  u16* Whhi  = (u16*)(ws + nxt(1024ul * 1024 * 2));
  u16* Whlo  = (u16*)(ws + nxt(1024ul * 1024 * 2));
  float* xp  = (float*)(ws + nxt(4096ul * 1024 * 4));
  u32* hpk   = (u32*)(ws + nxt(2ul * 4 * 512 * 4));
  int* ctr   = (int*)(ws + nxt(256));
  u16* hid_b = (u16*)(ws + nxt(4096ul * 1024 * 2));
  u16* Wro_b = (u16*)(ws + nxt(1024ul * 1024 * 2));
  u16* Wq_b  = (u16*)(ws + nxt(512ul * 1024 * 2));
  u16* Wk_b  = (u16*)(ws + nxt(512ul * 1024 * 2));
  u16* Wv_b  = (u16*)(ws + nxt(512ul * 1024 * 2));
  u16* Wao_b = (u16*)(ws + nxt(1024ul * 512 * 2));
  u16* Wlm_b = (u16*)(ws + nxt(32000ul * 1024 * 2));
  u16* outs_b= (u16*)(ws + nxt(4096ul * 1024 * 2));
  u16* q_b   = (u16*)(ws + nxt(4096ul * 512 * 2));
  u16* k_b   = (u16*)(ws + nxt(4096ul * 512 * 2));
  u16* vT_b  = (u16*)(ws + nxt(4ul * 512 * 1024 * 2));
  float* S   = (float*)(ws + nxt(4ul * 1024 * 1024 * 4));
  u16* P_b   = (u16*)(ws + nxt(4ul * 1024 * 1024 * 2));
  u16* at_b  = (u16*)(ws + nxt(4096ul * 512 * 2));
  u16* ao_b  = (u16*)(ws + nxt(4096ul * 1024 * 2));

  float* hidden_f = out + 131072000L;  // after logits
  float* outs_f   = out + 135266304L;  // after hidden

  (void)hipMemsetAsync(ctr, 0, 256, stream);

  // input prep
  embed_split_k<<<4096, 128, 0, stream>>>(tokens, emb, xhi, xlo);
  split_f32_k<<<512, 256, 0, stream>>>(Wi, Wihi, Wilo, 131072);
  split_f32_k<<<1024, 256, 0, stream>>>(Wh, Whhi, Whlo, 262144);
  cast_f32_k<<<1024, 256, 0, stream>>>(Wro, Wro_b, 262144);
  cast_f32_k<<<512, 256, 0, stream>>>(Wq, Wq_b, 131072);
  cast_f32_k<<<512, 256, 0, stream>>>(Wk, Wk_b, 131072);
  cast_f32_k<<<512, 256, 0, stream>>>(Wv, Wv_b, 131072);
  cast_f32_k<<<512, 256, 0, stream>>>(Wao, Wao_b, 131072);
  cast_f32_k<<<32000, 256, 0, stream>>>(Wlm, Wlm_b, 8192000);

  const dim3 blk(256);
  // xp = x @ Wi^T + bi  (split-bf16, 3 passes -> fp32-grade)
  gemm_nt<<<dim3(8, 32, 1), blk, 0, stream>>>(xhi, Wihi, xp, nullptr, bi, nullptr,
                                              1.f, 4096, 1024, 512, 0, 0, 0, 0, 0);
  gemm_nt<<<dim3(8, 32, 1), blk, 0, stream>>>(xhi, Wilo, xp, nullptr, nullptr, nullptr,
                                              1.f, 4096, 1024, 512, 0, 0, 0, 0, 1);
  gemm_nt<<<dim3(8, 32, 1), blk, 0, stream>>>(xlo, Wihi, xp, nullptr, nullptr, nullptr,
                                              1.f, 4096, 1024, 512, 0, 0, 0, 0, 1);
  // recurrence
  rnn_scan<<<16, blk, 0, stream>>>(Whhi, Whlo, xp, bh, hpk, ctr, hidden_f, hid_b);
  // outs = hidden @ Wro^T + bro  (fp32 out + bf16 copy)
  gemm_nt<<<dim3(8, 32, 1), blk, 0, stream>>>(hid_b, Wro_b, outs_f, outs_b, bro,
                                              nullptr, 1.f, 4096, 1024, 1024,
                                              0, 0, 0, 0, 0);
  // q = (outs @ Wq^T + bq)/sqrt(512); k = outs @ Wk^T + bk
  gemm_nt<<<dim3(4, 32, 1), blk, 0, stream>>>(outs_b, Wq_b, nullptr, q_b, bq, nullptr,
                                              0.044194173824159216f, 4096, 512, 1024,
                                              0, 0, 0, 0, 0);
  gemm_nt<<<dim3(4, 32, 1), blk, 0, stream>>>(outs_b, Wk_b, nullptr, k_b, bk, nullptr,
                                              1.f, 4096, 512, 1024, 0, 0, 0, 0, 0);
  // vT[b] = Wv @ outs[b]^T + bv (row bias)  -> v transposed per batch
  gemm_nt<<<dim3(8, 4, 4), blk, 0, stream>>>(Wv_b, outs_b, nullptr, vT_b, nullptr, bv,
                                             1.f, 512, 1024, 1024,
                                             0, 1048576, 0, 524288, 0);
  // S[b] = q[b] @ k[b]^T
  gemm_nt<<<dim3(8, 8, 4), blk, 0, stream>>>(q_b, k_b, S, nullptr, nullptr, nullptr,
                                             1.f, 1024, 1024, 512,
                                             524288, 524288, 1048576, 0, 0);
  softmax_causal_k<<<4096, 256, 0, stream>>>(S, P_b);
  // attn[b] = P[b] @ vT[b]^T
  gemm_nt<<<dim3(4, 8, 4), blk, 0, stream>>>(P_b, vT_b, nullptr, at_b, nullptr, nullptr,
                                             1.f, 1024, 512, 1024,
                                             1048576, 524288, 0, 524288, 0);
  // attn_out = attn @ Wao^T + bao
  gemm_nt<<<dim3(8, 32, 1), blk, 0, stream>>>(at_b, Wao_b, nullptr, ao_b, bao, nullptr,
                                              1.f, 4096, 1024, 512, 0, 0, 0, 0, 0);
  // logits = attn_out @ Wlm^T + blm
  gemm_nt<<<dim3(250, 32, 1), blk, 0, stream>>>(ao_b, Wlm_b, out, nullptr, blm, nullptr,
                                                1.f, 4096, 32000, 1024, 0, 0, 0, 0, 0);
}